// Round 1
// baseline (327.146 us; speedup 1.0000x reference)
//
#include <hip/hip_runtime.h>

// LinearSelfAttention B=32 P=4 N=1024 D=256, fused linear-attention pipeline.
// Round-N restructure: algebraic factorization of the context vector.
//   cv = sum_n softmax(q)_n * k_n  =  (y/S) @ Wk + b_k   with  y = sum_n e_n x_n
// so K is never materialized and V is recomputed instead of round-tripped:
//   k_prep: pack Wv/Wo bf16 fragments, wq fp32, zero y/S.
//   k_sum : streaming x pass: q GEMV -> e=exp(q+bq) -> y += e*x (fp32), S += e.
//   k_cv  : cv_g = (y_g/S_g) @ Wk + b_k  (fp32, 128x256 tiny transform).
//   k_vo  : v = relu(x@Wv + b_v) * cv -> LDS -> out = v@Wo + b_o (one x read,
//           one out write; no Vw intermediate, workspace 67.6MB -> 0.51MB).
// GEMMs: mfma_f32_16x16x32_bf16, B pre-packed in fragment order
//   frag[ct][kk][lane][j] = W[kk*32+(lane>>4)*8+j][ct*16+(lane&15)]
// C/D: col = ct*16+(lane&15), row = rt*16+(lane>>4)*4+reg.
// A-tiles staged in LDS bf16, XOR-swizzled 16B chunks: (row,c) at c^(row&15).

typedef float  floatx4 __attribute__((ext_vector_type(4)));
typedef __bf16 bf16x8  __attribute__((ext_vector_type(8)));
typedef unsigned short u16;
typedef u16 u16x8 __attribute__((ext_vector_type(8)));

#define NGRP 128

__device__ __forceinline__ float bf2f(u16 u) {
    union { unsigned int i; float f; } c; c.i = ((unsigned int)u) << 16; return c.f;
}
__device__ __forceinline__ u16 f2bf(float f) {
    union { __bf16 h; u16 u; } c; c.h = (__bf16)f; return c.u;
}
__device__ __forceinline__ floatx4 mfma16(bf16x8 a, bf16x8 b, floatx4 c) {
    return __builtin_amdgcn_mfma_f32_16x16x32_bf16(a, b, c, 0, 0, 0);
}

// ---------------------------------------------------------------------------
// k_prep: repack weights + zero accumulators. Grid 256 x 256 (i covers 65536
// = 16 tiles x 4096 for both Wv and Wo packs).
// ---------------------------------------------------------------------------
__global__ __launch_bounds__(256) void k_prep(
    const float* __restrict__ Wqkv, const float* __restrict__ Wo,
    u16* __restrict__ Wvp, u16* __restrict__ Wop,
    float* __restrict__ wqp, float* __restrict__ y, float* __restrict__ Sg)
{
    const int i = blockIdx.x * 256 + threadIdx.x;
    const int j = i & 7, lane = (i >> 3) & 63, kk = (i >> 9) & 7, ct = i >> 12;
    const int k = kk * 32 + (lane >> 4) * 8 + j;
    // v columns of Wqkv: 257 + ct*16 + n16  (ct in [0,16))
    Wvp[i] = f2bf(Wqkv[k * 513 + (257 + ct * 16 + (lane & 15))]);
    Wop[i] = f2bf(Wo[k * 256 + (ct * 16 + (lane & 15))]);
    if (i < 256) wqp[i] = Wqkv[i * 513];
    if (i < NGRP * 256) y[i] = 0.f;
    if (i < NGRP) Sg[i] = 0.f;
}

// ---------------------------------------------------------------------------
// k_sum: 2048 blocks x 256 threads, 64 rows/block. Pass A: q GEMV (4 threads
// per row, interleaved float4 so each wave instr is 16 rows x 64B contiguous),
// e = exp(q+bq) -> LDS. Pass B: thread d accumulates sum_r e_r*x[r][d] (fp32,
// L1/L2-warm re-read) -> one atomicAdd per column. Wave 0 reduces S.
// ---------------------------------------------------------------------------
__global__ __launch_bounds__(256) void k_sum(
    const float* __restrict__ x, const float* __restrict__ wqp,
    const float* __restrict__ bqkv,
    float* __restrict__ y, float* __restrict__ Sg)
{
    const int tid = threadIdx.x;
    const int m0 = blockIdx.x * 64;
    const int g  = blockIdx.x >> 4;
    __shared__ float e_s[64];

    // ---- pass A: q GEMV + exp ----
    {
        const int r = tid >> 2, s = tid & 3;
        const float* xp = x + (size_t)(m0 + r) * 256 + s * 4;
        const float* wp = wqp + s * 4;
        float q = 0.f;
#pragma unroll
        for (int j = 0; j < 16; j++) {
            floatx4 xv = *(const floatx4*)(xp + j * 16);
            floatx4 wv = *(const floatx4*)(wp + j * 16);
            q += xv[0] * wv[0] + xv[1] * wv[1] + xv[2] * wv[2] + xv[3] * wv[3];
        }
        q += __shfl_xor(q, 1, 64);
        q += __shfl_xor(q, 2, 64);
        if (s == 0) e_s[r] = __expf(q + bqkv[0]);
    }
    __syncthreads();

    // ---- S partial (wave 0) ----
    if (tid < 64) {
        float e = e_s[tid];
#pragma unroll
        for (int s = 32; s > 0; s >>= 1) e += __shfl_xor(e, s, 64);
        if (tid == 0) atomicAdd(Sg + g, e);
    }

    // ---- pass B: y_d += sum_r e_r * x[r][d] ----
    {
        float acc = 0.f;
        const float* xp = x + (size_t)m0 * 256 + tid;
#pragma unroll 8
        for (int r = 0; r < 64; r++) acc += e_s[r] * xp[r * 256];
        atomicAdd(y + g * 256 + tid, acc);
    }
}

// ---------------------------------------------------------------------------
// k_cv: cv_g = (y_g/S_g) @ Wk + b_k. 128 blocks x 256 threads; thread d does a
// 256-dot against Wqkv column (1+d), coalesced across d, L3-resident weights.
// ---------------------------------------------------------------------------
__global__ __launch_bounds__(256) void k_cv(
    const float* __restrict__ Wqkv, const float* __restrict__ bqkv,
    const float* __restrict__ y, const float* __restrict__ Sg,
    float* __restrict__ cv)
{
    const int g = blockIdx.x, d = threadIdx.x;
    __shared__ float ys[256];
    ys[d] = y[g * 256 + d] * (1.0f / Sg[g]);
    __syncthreads();
    float acc = bqkv[1 + d];
    const float* wp = Wqkv + 1 + d;
#pragma unroll 4
    for (int t = 0; t < 256; t++) acc += ys[t] * wp[t * 513];
    cv[g * 256 + d] = acc;
}

// ---------------------------------------------------------------------------
// k_vo: out = (relu(x@Wv+b_v) .* cv) @ Wo + b_o. 2048 blocks x 512 threads,
// Mtile=64, wave w owns col-tiles {w, w+8} in both GEMMs. The v tile is
// rescaled A-side (relu * cv) and written back into the same swizzled LDS
// buffer between the two MFMA phases.
// ---------------------------------------------------------------------------
__global__ __launch_bounds__(512, 4) void k_vo(
    const float* __restrict__ x, const u16* __restrict__ Wvp,
    const u16* __restrict__ Wop, const float* __restrict__ cv,
    const float* __restrict__ bqkv, const float* __restrict__ bo,
    float* __restrict__ out)
{
    const int tid = threadIdx.x;
    const int w = tid >> 6, lane = tid & 63, quad = lane >> 4, n16 = lane & 15;
    const int m0 = blockIdx.x * 64;
    const int g  = blockIdx.x >> 4;

    __shared__ u16 As[64 * 256];     // 32 KB, bf16 x-tile then v-tile, swizzled
    __shared__ float cvs[256];

    if (tid < 256) cvs[tid] = cv[g * 256 + tid];

    // ---- stage x tile -> bf16 LDS ----
#pragma unroll
    for (int it = 0; it < 4; it++) {
        const int c = it * 512 + tid;
        const int row = c >> 5, col = c & 31;
        const float* xp = x + (size_t)(m0 + row) * 256 + col * 8;
        floatx4 u0 = *(const floatx4*)xp;
        floatx4 u1 = *(const floatx4*)(xp + 4);
        u16x8 o;
        o[0] = f2bf(u0[0]); o[1] = f2bf(u0[1]); o[2] = f2bf(u0[2]); o[3] = f2bf(u0[3]);
        o[4] = f2bf(u1[0]); o[5] = f2bf(u1[1]); o[6] = f2bf(u1[2]); o[7] = f2bf(u1[3]);
        *(u16x8*)(As + row * 256 + ((col ^ (row & 15)) * 8)) = o;
    }
    __syncthreads();

    // ---- phase 1: v = x @ Wv ----
    floatx4 acc[2][4];
#pragma unroll
    for (int i = 0; i < 2; i++)
#pragma unroll
        for (int rt = 0; rt < 4; rt++) acc[i][rt] = (floatx4){0.f, 0.f, 0.f, 0.f};

#pragma unroll
    for (int kk = 0; kk < 8; kk++) {
        bf16x8 a[4];
#pragma unroll
        for (int rt = 0; rt < 4; rt++) {
            const int row = rt * 16 + n16;
            a[rt] = __builtin_bit_cast(bf16x8,
                *(const u16x8*)(As + row * 256 + (((kk * 4 + quad) ^ n16) * 8)));
        }
#pragma unroll
        for (int i = 0; i < 2; i++) {
            const int ct = w + 8 * i;
            bf16x8 b = __builtin_bit_cast(bf16x8,
                *(const u16x8*)(Wvp + (size_t)((ct * 8 + kk) * 64 + lane) * 8));
#pragma unroll
            for (int rt = 0; rt < 4; rt++) acc[i][rt] = mfma16(a[rt], b, acc[i][rt]);
        }
    }
    __syncthreads();   // all waves done reading x tile

    // ---- epilogue 1: v = relu(acc + b_v) * cv -> bf16, back into As ----
#pragma unroll
    for (int i = 0; i < 2; i++) {
        const int col = (w + 8 * i) * 16 + n16;
        const float bias = bqkv[257 + col];
        const float scale = cvs[col];
        const int cc = col >> 3, co = col & 7;
#pragma unroll
        for (int rt = 0; rt < 4; rt++) {
#pragma unroll
            for (int r = 0; r < 4; r++) {
                const int row = rt * 16 + quad * 4 + r;
                const float vv = fmaxf(acc[i][rt][r] + bias, 0.f) * scale;
                As[row * 256 + ((cc ^ (row & 15)) * 8) + co] = f2bf(vv);
            }
        }
    }
    __syncthreads();

    // ---- phase 2: out = v @ Wo ----
    floatx4 acc2[2][4];
#pragma unroll
    for (int i = 0; i < 2; i++)
#pragma unroll
        for (int rt = 0; rt < 4; rt++) acc2[i][rt] = (floatx4){0.f, 0.f, 0.f, 0.f};

#pragma unroll
    for (int kk = 0; kk < 8; kk++) {
        bf16x8 a[4];
#pragma unroll
        for (int rt = 0; rt < 4; rt++) {
            const int row = rt * 16 + n16;
            a[rt] = __builtin_bit_cast(bf16x8,
                *(const u16x8*)(As + row * 256 + (((kk * 4 + quad) ^ n16) * 8)));
        }
#pragma unroll
        for (int i = 0; i < 2; i++) {
            const int ct = w + 8 * i;
            bf16x8 b = __builtin_bit_cast(bf16x8,
                *(const u16x8*)(Wop + (size_t)((ct * 8 + kk) * 64 + lane) * 8));
#pragma unroll
            for (int rt = 0; rt < 4; rt++) acc2[i][rt] = mfma16(a[rt], b, acc2[i][rt]);
        }
    }

    // ---- epilogue 2: out write ----
#pragma unroll
    for (int i = 0; i < 2; i++) {
        const int col = (w + 8 * i) * 16 + n16;
        const float bias = bo[col];
#pragma unroll
        for (int rt = 0; rt < 4; rt++) {
            const int rowb = m0 + rt * 16 + quad * 4;
#pragma unroll
            for (int r = 0; r < 4; r++)
                out[(size_t)(rowb + r) * 256 + col] = acc2[i][rt][r] + bias;
        }
    }
}

// ---------------------------------------------------------------------------
extern "C" void kernel_launch(void* const* d_in, const int* in_sizes, int n_in,
                              void* d_out, int out_size, void* d_ws, size_t ws_size,
                              hipStream_t stream)
{
    const float* x    = (const float*)d_in[0];
    const float* Wqkv = (const float*)d_in[1];
    const float* bqkv = (const float*)d_in[2];
    const float* Wo   = (const float*)d_in[3];
    const float* bo   = (const float*)d_in[4];
    float* out = (float*)d_out;

    char* ws = (char*)d_ws;
    u16*   Wvp = (u16*)(ws);                 // 131,072 B
    u16*   Wop = (u16*)(ws + 131072);        // 131,072 B
    float* wqp = (float*)(ws + 262144);      //   1,024 B
    float* y   = (float*)(ws + 263168);      // 131,072 B
    float* Sg  = (float*)(ws + 394240);      //     512 B
    float* cv  = (float*)(ws + 394752);      // 131,072 B
                                             // total 525,824 B

    k_prep<<<256,  256, 0, stream>>>(Wqkv, Wo, Wvp, Wop, wqp, y, Sg);
    k_sum <<<2048, 256, 0, stream>>>(x, wqp, bqkv, y, Sg);
    k_cv  <<<NGRP, 256, 0, stream>>>(Wqkv, bqkv, y, Sg, cv);
    k_vo  <<<2048, 512, 0, stream>>>(x, Wvp, Wop, cv, bqkv, bo, out);
}

// Round 2
// 320.399 us; speedup vs baseline: 1.0211x; 1.0211x over previous
//
#include <hip/hip_runtime.h>

// LinearSelfAttention B=32 P=4 N=1024 D=256.
// cv = sum_n softmax(q)_n k_n = (y/S)@Wk + b_k, y = sum_n e_n x_n  (K never formed).
//   k_prep: pack Wv/Wo bf16 MFMA fragments, wq fp32, zero y/S.
//   k_sum : stream x: q GEMV -> e=exp(q+bq); y += e*x (atomics); S += e;
//           ALSO writes xb = bf16 XOR-swizzled LDS-image of each 64-row tile
//           (pre-swizzled source so k_vo can DMA it linearly, G21).
//   k_vo  : per block: cv = (y/S)@Wk + b_k (fp32, overlaps tile-0 DMA), then
//           4 m-tiles pipelined: DMA(t+1)->As[nxt] || {phase1 x@Wv, epi1
//           relu*cv -> As[cur], phase2 v@Wo, out}. Raw lgkmcnt barriers keep
//           the DMA in flight across intra-tile phases; one full __syncthreads
//           per tile drains it. Out-stores issued after the drain barrier so
//           they overlap the next tile's phase 1.
// GEMMs: mfma_f32_16x16x32_bf16, B pre-packed in fragment order
//   frag[ct][kk][lane][j] = W[kk*32+(lane>>4)*8+j][ct*16+(lane&15)]
// C/D: col = ct*16+(lane&15), row = rt*16+(lane>>4)*4+reg.
// LDS x/v tile swizzle: 16B chunk (row,c) stored at chunk index c^(row&15).

typedef float  floatx4 __attribute__((ext_vector_type(4)));
typedef __bf16 bf16x8  __attribute__((ext_vector_type(8)));
typedef unsigned short u16;
typedef u16 u16x8 __attribute__((ext_vector_type(8)));

#define NGRP 128

__device__ __forceinline__ float bf2f(u16 u) {
    union { unsigned int i; float f; } c; c.i = ((unsigned int)u) << 16; return c.f;
}
__device__ __forceinline__ u16 f2bf(float f) {
    union { __bf16 h; u16 u; } c; c.h = (__bf16)f; return c.u;
}
__device__ __forceinline__ floatx4 mfma16(bf16x8 a, bf16x8 b, floatx4 c) {
    return __builtin_amdgcn_mfma_f32_16x16x32_bf16(a, b, c, 0, 0, 0);
}

// Raw barrier: drains this wave's LDS ops but leaves global_load_lds /
// global_store traffic in flight (no vmcnt drain, unlike __syncthreads()).
__device__ __forceinline__ void bar_lgkm() {
    __builtin_amdgcn_sched_barrier(0);
    asm volatile("s_waitcnt lgkmcnt(0)" ::: "memory");
    __builtin_amdgcn_s_barrier();
    __builtin_amdgcn_sched_barrier(0);
}

// 16B global->LDS DMA. lds must be wave-uniform; HW adds lane*16.
__device__ __forceinline__ void dma16(const u16* src, u16* lds) {
    __builtin_amdgcn_global_load_lds(
        (const __attribute__((address_space(1))) unsigned int*)src,
        (__attribute__((address_space(3))) unsigned int*)lds, 16, 0, 0);
}

// ---------------------------------------------------------------------------
// k_prep: repack weights + zero accumulators. Grid 256 x 256.
// ---------------------------------------------------------------------------
__global__ __launch_bounds__(256) void k_prep(
    const float* __restrict__ Wqkv, const float* __restrict__ Wo,
    u16* __restrict__ Wvp, u16* __restrict__ Wop,
    float* __restrict__ wqp, float* __restrict__ y, float* __restrict__ Sg)
{
    const int i = blockIdx.x * 256 + threadIdx.x;
    const int j = i & 7, lane = (i >> 3) & 63, kk = (i >> 9) & 7, ct = i >> 12;
    const int k = kk * 32 + (lane >> 4) * 8 + j;
    Wvp[i] = f2bf(Wqkv[k * 513 + (257 + ct * 16 + (lane & 15))]);
    Wop[i] = f2bf(Wo[k * 256 + (ct * 16 + (lane & 15))]);
    if (i < 256) wqp[i] = Wqkv[i * 513];
    if (i < NGRP * 256) y[i] = 0.f;
    if (i < NGRP) Sg[i] = 0.f;
}

// ---------------------------------------------------------------------------
// k_sum: 2048 blocks x 256 threads, 64 rows each.
//   A: q GEMV (4 thr/row) -> e_s;  C: x -> bf16 swizzled image xb (L2 re-read);
//   S reduce; B: y_d += sum_r e_r * x[r][d] -> one atomic per column.
// ---------------------------------------------------------------------------
__global__ __launch_bounds__(256) void k_sum(
    const float* __restrict__ x, const float* __restrict__ wqp,
    const float* __restrict__ bqkv,
    float* __restrict__ y, float* __restrict__ Sg, u16* __restrict__ xb)
{
    const int tid = threadIdx.x;
    const int m0 = blockIdx.x * 64;
    const int g  = blockIdx.x >> 4;
    __shared__ float e_s[64];

    // ---- pass A: q GEMV + exp ----
    {
        const int r = tid >> 2, s = tid & 3;
        const float* xp = x + (size_t)(m0 + r) * 256 + s * 4;
        const float* wp = wqp + s * 4;
        float q = 0.f;
#pragma unroll
        for (int j = 0; j < 16; j++) {
            floatx4 xv = *(const floatx4*)(xp + j * 16);
            floatx4 wv = *(const floatx4*)(wp + j * 16);
            q += xv[0] * wv[0] + xv[1] * wv[1] + xv[2] * wv[2] + xv[3] * wv[3];
        }
        q += __shfl_xor(q, 1, 64);
        q += __shfl_xor(q, 2, 64);
        if (s == 0) e_s[r] = __expf(q + bqkv[0]);
    }

    // ---- pass C: bf16 swizzled tile image -> xb (independent of e_s) ----
    {
        u16* xt = xb + (size_t)blockIdx.x * 16384;
#pragma unroll
        for (int i = 0; i < 8; i++) {
            const int chunk = i * 256 + tid;
            const int row = chunk >> 5, col = chunk & 31;
            const float* xp = x + (size_t)(m0 + row) * 256 + col * 8;
            floatx4 u0 = *(const floatx4*)xp;
            floatx4 u1 = *(const floatx4*)(xp + 4);
            u16x8 o;
            o[0] = f2bf(u0[0]); o[1] = f2bf(u0[1]); o[2] = f2bf(u0[2]); o[3] = f2bf(u0[3]);
            o[4] = f2bf(u1[0]); o[5] = f2bf(u1[1]); o[6] = f2bf(u1[2]); o[7] = f2bf(u1[3]);
            *(u16x8*)(xt + row * 256 + ((col ^ (row & 15)) * 8)) = o;
        }
    }
    __syncthreads();

    // ---- S partial (wave 0) ----
    if (tid < 64) {
        float e = e_s[tid];
#pragma unroll
        for (int s = 32; s > 0; s >>= 1) e += __shfl_xor(e, s, 64);
        if (tid == 0) atomicAdd(Sg + g, e);
    }

    // ---- pass B: y_d += sum_r e_r * x[r][d] ----
    {
        float acc = 0.f;
        const float* xp = x + (size_t)m0 * 256 + tid;
#pragma unroll 8
        for (int r = 0; r < 64; r++) acc += e_s[r] * xp[r * 256];
        atomicAdd(y + g * 256 + tid, acc);
    }
}

// ---------------------------------------------------------------------------
// k_vo: out = (relu(x@Wv+b_v) .* cv) @ Wo + b_o.
// 512 blocks x 512 threads; block b: group g=b>>2, 4 m-tiles b*4..b*4+3,
// double-buffered LDS + global_load_lds prefetch. cv computed per block in
// the prologue (overlaps tile-0 DMA).
// ---------------------------------------------------------------------------
__global__ __launch_bounds__(512, 4) void k_vo(
    const u16* __restrict__ xb, const u16* __restrict__ Wvp,
    const u16* __restrict__ Wop, const float* __restrict__ y,
    const float* __restrict__ Sg, const float* __restrict__ Wqkv,
    const float* __restrict__ bqkv, const float* __restrict__ bo,
    float* __restrict__ out)
{
    const int tid = threadIdx.x;
    const int w = tid >> 6, lane = tid & 63, quad = lane >> 4, n16 = lane & 15;
    const int b = blockIdx.x;
    const int g = b >> 2;
    const int tile0 = b * 4;

    __shared__ u16 As[2][16384];     // 2 x 32 KB swizzled x/v tile
    __shared__ float ys[256];
    __shared__ float cvh[2][256];

    // ---- issue DMA for tile0 -> As[0] (in flight through cv compute) ----
    {
        const u16* src = xb + (size_t)tile0 * 16384;
#pragma unroll
        for (int i = 0; i < 4; i++)
            dma16(src + (size_t)(i * 512 + tid) * 8, &As[0][(i * 512 + w * 64) * 8]);
    }

    // ---- ys = y/S ----
    const float rS = 1.0f / Sg[g];
    if (tid < 256) ys[tid] = y[g * 256 + tid] * rS;
    bar_lgkm();                          // ys visible; DMA0 still in flight

    // ---- cv halves: cv_d = b_k[d] + sum_t ys[t] * Wk[t][d] ----
    {
        const int d = tid & 255, half = tid >> 8;
        float cvacc = (half == 0) ? bqkv[1 + d] : 0.f;
        const float* wp = Wqkv + (size_t)(half * 128) * 513 + 1 + d;
        const float* yp = ys + half * 128;
#pragma unroll 4
        for (int t = 0; t < 128; t++) cvacc += yp[t] * wp[(size_t)t * 513];
        cvh[half][d] = cvacc;
    }
    __syncthreads();                     // cvh visible AND tile-0 DMA drained

    // ---- per-wave loop-invariant epilogue constants ----
    float bvv[2], scv[2], bov[2];
#pragma unroll
    for (int i = 0; i < 2; i++) {
        const int col = (w + 8 * i) * 16 + n16;
        bvv[i] = bqkv[257 + col];
        scv[i] = cvh[0][col] + cvh[1][col];
        bov[i] = bo[col];
    }

    // ---- 4-tile pipelined main loop ----
#pragma unroll
    for (int it = 0; it < 4; ++it) {
        const int cur = it & 1, nxt = cur ^ 1;
        const int m0 = (tile0 + it) * 64;

        // issue prefetch of next tile (stays in flight until __syncthreads)
        if (it < 3) {
            const u16* src = xb + (size_t)(tile0 + it + 1) * 16384;
#pragma unroll
            for (int i = 0; i < 4; i++)
                dma16(src + (size_t)(i * 512 + tid) * 8,
                      &As[nxt][(i * 512 + w * 64) * 8]);
        }

        // phase 1: v = x @ Wv
        floatx4 acc[2][4];
#pragma unroll
        for (int i = 0; i < 2; i++)
#pragma unroll
            for (int rt = 0; rt < 4; rt++) acc[i][rt] = (floatx4){0.f, 0.f, 0.f, 0.f};
#pragma unroll
        for (int kk = 0; kk < 8; kk++) {
            bf16x8 a[4];
#pragma unroll
            for (int rt = 0; rt < 4; rt++) {
                const int row = rt * 16 + n16;
                a[rt] = __builtin_bit_cast(bf16x8,
                    *(const u16x8*)(&As[cur][row * 256 + (((kk * 4 + quad) ^ n16) * 8)]));
            }
#pragma unroll
            for (int i = 0; i < 2; i++) {
                const int ct = w + 8 * i;
                bf16x8 bfr = __builtin_bit_cast(bf16x8,
                    *(const u16x8*)(Wvp + (size_t)((ct * 8 + kk) * 64 + lane) * 8));
#pragma unroll
                for (int rt = 0; rt < 4; rt++) acc[i][rt] = mfma16(a[rt], bfr, acc[i][rt]);
            }
        }
        bar_lgkm();                      // phase-1 LDS reads done; DMA unharmed

        // epilogue 1: v = relu(acc + b_v) * cv -> bf16, back into As[cur]
#pragma unroll
        for (int i = 0; i < 2; i++) {
            const int col = (w + 8 * i) * 16 + n16;
            const int cc = col >> 3, co = col & 7;
#pragma unroll
            for (int rt = 0; rt < 4; rt++) {
#pragma unroll
                for (int r = 0; r < 4; r++) {
                    const int row = rt * 16 + quad * 4 + r;
                    As[cur][row * 256 + ((cc ^ (row & 15)) * 8) + co] =
                        f2bf(fmaxf(acc[i][rt][r] + bvv[i], 0.f) * scv[i]);
                }
            }
        }
        bar_lgkm();                      // v writes visible; DMA unharmed

        // phase 2: out = v @ Wo
        floatx4 acc2[2][4];
#pragma unroll
        for (int i = 0; i < 2; i++)
#pragma unroll
            for (int rt = 0; rt < 4; rt++) acc2[i][rt] = (floatx4){0.f, 0.f, 0.f, 0.f};
#pragma unroll
        for (int kk = 0; kk < 8; kk++) {
            bf16x8 a[4];
#pragma unroll
            for (int rt = 0; rt < 4; rt++) {
                const int row = rt * 16 + n16;
                a[rt] = __builtin_bit_cast(bf16x8,
                    *(const u16x8*)(&As[cur][row * 256 + (((kk * 4 + quad) ^ n16) * 8)]));
            }
#pragma unroll
            for (int i = 0; i < 2; i++) {
                const int ct = w + 8 * i;
                bf16x8 bfr = __builtin_bit_cast(bf16x8,
                    *(const u16x8*)(Wop + (size_t)((ct * 8 + kk) * 64 + lane) * 8));
#pragma unroll
                for (int rt = 0; rt < 4; rt++) acc2[i][rt] = mfma16(a[rt], bfr, acc2[i][rt]);
            }
        }

        // full drain: next-tile DMA complete, phase-2 LDS reads complete,
        // previous iteration's out-stores long gone.
        __syncthreads();

        // epilogue 2: out stores AFTER the barrier -> overlap next phase 1
#pragma unroll
        for (int i = 0; i < 2; i++) {
            const int col = (w + 8 * i) * 16 + n16;
#pragma unroll
            for (int rt = 0; rt < 4; rt++) {
                const int rowb = m0 + rt * 16 + quad * 4;
#pragma unroll
                for (int r = 0; r < 4; r++)
                    out[(size_t)(rowb + r) * 256 + col] = acc2[i][rt][r] + bov[i];
            }
        }
    }
}

// ---------------------------------------------------------------------------
extern "C" void kernel_launch(void* const* d_in, const int* in_sizes, int n_in,
                              void* d_out, int out_size, void* d_ws, size_t ws_size,
                              hipStream_t stream)
{
    const float* x    = (const float*)d_in[0];
    const float* Wqkv = (const float*)d_in[1];
    const float* bqkv = (const float*)d_in[2];
    const float* Wo   = (const float*)d_in[3];
    const float* bo   = (const float*)d_in[4];
    float* out = (float*)d_out;

    char* ws = (char*)d_ws;
    u16*   Wvp = (u16*)(ws);                 //    131,072 B
    u16*   Wop = (u16*)(ws + 131072);        //    131,072 B
    float* wqp = (float*)(ws + 262144);      //      1,024 B
    float* y   = (float*)(ws + 263168);      //    131,072 B
    float* Sg  = (float*)(ws + 394240);      //        512 B
    u16*   xb  = (u16*)(ws + 394752);        // 67,108,864 B (bf16 swizzled x)
                                             // total 67,503,616 B

    k_prep<<<256,  256, 0, stream>>>(Wqkv, Wo, Wvp, Wop, wqp, y, Sg);
    k_sum <<<2048, 256, 0, stream>>>(x, wqp, bqkv, y, Sg, xb);
    k_vo  <<<512,  512, 0, stream>>>(xb, Wvp, Wop, y, Sg, Wqkv, bqkv, bo, out);
}